// Round 4
// baseline (373.361 us; speedup 1.0000x reference)
//
#include <hip/hip_runtime.h>
#include <hip/hip_fp16.h>

#define MDIM 32
#define KDIM 8192
#define NDIM 8192
#define NT 128            // columns per workgroup
#define KC 512            // k-rows per workgroup (16 k-splits)
#define BK 64             // k-rows per LDS tile
#define NTILES (KC / BK)  // 8
#define WSTRIDE 72        // f16 per LDS n-row (144 B): keeps b128 reads aligned+conflict-free

typedef __fp16 half8 __attribute__((ext_vector_type(8)));
typedef float f32x4 __attribute__((ext_vector_type(4)));

__device__ __forceinline__ unsigned pk_u32(float a, float b) {
#if __has_builtin(__builtin_amdgcn_cvt_pkrtz)
  return __builtin_bit_cast(unsigned, __builtin_amdgcn_cvt_pkrtz(a, b));
#else
  __fp16 r2[2] = {(__fp16)a, (__fp16)b};
  return __builtin_bit_cast(unsigned, r2);
#endif
}

// ---------- pre-pass: pack x[32][8192] f32 -> A-fragment-major f16 ----------
// Layout: uint4 index T = (sg*2 + mt)*64 + lane; element j of the half8 is
// x[mt*16 + (lane&15)][sg*32 + (lane>>4)*8 + j]  (exact MFMA A-operand order).
__global__ __launch_bounds__(256) void xpack_kernel(const float* __restrict__ x,
                                                    uint4* __restrict__ xpf) {
  const int T  = blockIdx.x * 256 + threadIdx.x;   // 0..32767
  const int sg = T >> 7;
  const int r  = T & 127;
  const int mt = r >> 6;
  const int L  = r & 63;
  const int m  = mt * 16 + (L & 15);
  const int k  = sg * 32 + (L >> 4) * 8;
  const float4* p = reinterpret_cast<const float4*>(x + (size_t)m * KDIM + k);
  float4 u0 = p[0], u1 = p[1];
  uint4 o;
  o.x = pk_u32(u0.x, u0.y);
  o.y = pk_u32(u0.z, u0.w);
  o.z = pk_u32(u1.x, u1.y);
  o.w = pk_u32(u1.z, u1.w);
  xpf[T] = o;
}

// ---------- fused Q4_0 fake-quant + MFMA GEMM ----------
// grid = (NDIM/NT, KDIM/KC) = (64,16), block = 256 (4 waves).
__global__ __launch_bounds__(256, 4) void fused_q4_gemm(
    const uint4* __restrict__ xpf,     // packed x fragments
    const float* __restrict__ w,       // [8192][8192]
    const float* __restrict__ bias,    // [8192]
    float* __restrict__ out)           // [32][8192]
{
  __shared__ _Float16 s_w[NT * WSTRIDE];   // 18.4 KB, [n][k] f16, stride 72

  const int t  = threadIdx.x;
  const int n0 = blockIdx.x * NT;
  const int k0 = blockIdx.y * KC;

  // phase-A mapping: 2 k-rows x 16 cols per thread
  const int kr = t >> 3;               // k-pair row 0..31
  const int nc = t & 7;                // 16-col half-block 0..7

  // phase-B mapping
  const int lane = t & 63;
  const int wv   = t >> 6;             // wave 0..3 -> n-subrange wv*32
  const int l15  = lane & 15;
  const int q    = lane >> 4;

  f32x4 acc00 = {0.f, 0.f, 0.f, 0.f};  // (mt0, ns0)
  f32x4 acc01 = {0.f, 0.f, 0.f, 0.f};  // (mt0, ns1)
  f32x4 acc10 = {0.f, 0.f, 0.f, 0.f};  // (mt1, ns0)
  f32x4 acc11 = {0.f, 0.f, 0.f, 0.f};  // (mt1, ns1)

  unsigned* sw32 = reinterpret_cast<unsigned*>(s_w);

  for (int tt = 0; tt < NTILES; ++tt) {
    const int kt = k0 + tt * BK;

    // ---- Phase A: load, exact block-scale, dequant, stage f16 to LDS [n][k] ----
    {
      const float* rp = w + (size_t)(kt + 2 * kr) * NDIM + n0 + nc * 16;
      float4 v0[4], v1[4];
#pragma unroll
      for (int j = 0; j < 4; ++j) {
        v0[j] = reinterpret_cast<const float4*>(rp)[j];
        v1[j] = reinterpret_cast<const float4*>(rp + NDIM)[j];
      }
      float ba0 = -1.0f, bv0 = 0.0f, ba1 = -1.0f, bv1 = 0.0f;
#pragma unroll
      for (int j = 0; j < 4; ++j) {
        float c, a;
        c = v0[j].x; a = fabsf(c); if (a > ba0) { ba0 = a; bv0 = c; }
        c = v0[j].y; a = fabsf(c); if (a > ba0) { ba0 = a; bv0 = c; }
        c = v0[j].z; a = fabsf(c); if (a > ba0) { ba0 = a; bv0 = c; }
        c = v0[j].w; a = fabsf(c); if (a > ba0) { ba0 = a; bv0 = c; }
        c = v1[j].x; a = fabsf(c); if (a > ba1) { ba1 = a; bv1 = c; }
        c = v1[j].y; a = fabsf(c); if (a > ba1) { ba1 = a; bv1 = c; }
        c = v1[j].z; a = fabsf(c); if (a > ba1) { ba1 = a; bv1 = c; }
        c = v1[j].w; a = fabsf(c); if (a > ba1) { ba1 = a; bv1 = c; }
      }
      // combine with partner half-block (t^1); even half holds earlier cols (wins ties)
      float pa0 = __shfl_xor(ba0, 1), pv0 = __shfl_xor(bv0, 1);
      float pa1 = __shfl_xor(ba1, 1), pv1 = __shfl_xor(bv1, 1);
      const bool odd = (t & 1);
      if (odd ? (pa0 >= ba0) : (pa0 > ba0)) bv0 = pv0;
      if (odd ? (pa1 >= ba1) : (pa1 > ba1)) bv1 = pv1;

      float d0 = bv0 * -0.125f;
      float i0 = (d0 == 0.0f) ? 0.0f : 1.0f / d0;   // exact fp32 divide
      float s0 = __half2float(__float2half(d0));    // fp16 RTNE round-trip
      float d1 = bv1 * -0.125f;
      float i1 = (d1 == 0.0f) ? 0.0f : 1.0f / d1;
      float s1 = __half2float(__float2half(d1));

      unsigned pw[16];
#pragma unroll
      for (int j = 0; j < 4; ++j) {
        float qv, a0f, a1f;
#define DQ(comp, idx)                                                        \
        qv = fminf(fmaxf(truncf(fmaf(v0[j].comp, i0, 8.5f)), 0.0f), 15.0f);  \
        a0f = (qv - 8.0f) * s0;                                              \
        qv = fminf(fmaxf(truncf(fmaf(v1[j].comp, i1, 8.5f)), 0.0f), 15.0f);  \
        a1f = (qv - 8.0f) * s1;                                              \
        pw[j * 4 + idx] = pk_u32(a0f, a1f);
        DQ(x, 0) DQ(y, 1) DQ(z, 2) DQ(w, 3)
#undef DQ
      }
      // scatter k-pair (2*kr, 2*kr+1) into 16 n-rows: b32 writes, stride 36 words
#pragma unroll
      for (int i = 0; i < 16; ++i) {
        const int n = nc * 16 + i;
        sw32[n * (WSTRIDE / 2) + kr] = pw[i];
      }
    }

    __syncthreads();

    // ---- Phase B: MFMA. A from packed global x, B from LDS. ----
    const int sgbase = kt >> 5;   // global 32-k-step index
#pragma unroll
    for (int ks = 0; ks < 2; ++ks) {
      const uint4* ap = xpf + ((size_t)(sgbase + ks) * 2) * 64 + lane;
      uint4 a0u = ap[0];          // mt = 0
      uint4 a1u = ap[64];         // mt = 1
      const int kl = ks * 32 + q * 8;
      uint4 b0u = *reinterpret_cast<const uint4*>(&s_w[(wv * 32 + l15) * WSTRIDE + kl]);
      uint4 b1u = *reinterpret_cast<const uint4*>(&s_w[(wv * 32 + 16 + l15) * WSTRIDE + kl]);
      half8 a0 = __builtin_bit_cast(half8, a0u);
      half8 a1 = __builtin_bit_cast(half8, a1u);
      half8 b0 = __builtin_bit_cast(half8, b0u);
      half8 b1 = __builtin_bit_cast(half8, b1u);
      acc00 = __builtin_amdgcn_mfma_f32_16x16x32_f16(a0, b0, acc00, 0, 0, 0);
      acc01 = __builtin_amdgcn_mfma_f32_16x16x32_f16(a0, b1, acc01, 0, 0, 0);
      acc10 = __builtin_amdgcn_mfma_f32_16x16x32_f16(a1, b0, acc10, 0, 0, 0);
      acc11 = __builtin_amdgcn_mfma_f32_16x16x32_f16(a1, b1, acc11, 0, 0, 0);
    }
    __syncthreads();
  }

  // ---- epilogue: k-split partials via atomics; split 0 folds bias ----
  const int gn0 = n0 + wv * 32 + l15;
  const int gn1 = gn0 + 16;
  const float bv0 = (blockIdx.y == 0) ? bias[gn0] : 0.0f;
  const float bv1 = (blockIdx.y == 0) ? bias[gn1] : 0.0f;
#pragma unroll
  for (int r = 0; r < 4; ++r) {
    const int m0 = q * 4 + r;         // mt = 0 rows
    const int m1 = 16 + q * 4 + r;    // mt = 1 rows
    atomicAdd(out + (size_t)m0 * NDIM + gn0, acc00[r] + bv0);
    atomicAdd(out + (size_t)m0 * NDIM + gn1, acc01[r] + bv1);
    atomicAdd(out + (size_t)m1 * NDIM + gn0, acc10[r] + bv0);
    atomicAdd(out + (size_t)m1 * NDIM + gn1, acc11[r] + bv1);
  }
}

extern "C" void kernel_launch(void* const* d_in, const int* in_sizes, int n_in,
                              void* d_out, int out_size, void* d_ws, size_t ws_size,
                              hipStream_t stream) {
  const float* x    = (const float*)d_in[0];   // [1,32,8192] f32
  const float* w    = (const float*)d_in[1];   // [8192,8192] f32
  const float* bias = (const float*)d_in[2];   // [8192] f32
  float* out  = (float*)d_out;                 // [1,32,8192] f32
  uint4* xpf  = (uint4*)d_ws;                  // 512 KB packed x fragments

  (void)hipMemsetAsync(out, 0, (size_t)MDIM * NDIM * sizeof(float), stream);
  xpack_kernel<<<128, 256, 0, stream>>>(x, xpf);

  dim3 grid(NDIM / NT, KDIM / KC);
  fused_q4_gemm<<<grid, 256, 0, stream>>>(xpf, w, bias, out);
}

// Round 6
// 362.327 us; speedup vs baseline: 1.0305x; 1.0305x over previous
//
#include <hip/hip_runtime.h>
#include <hip/hip_fp16.h>

#define MDIM 32
#define KDIM 8192
#define NDIM 8192
#define NT 128            // columns per workgroup
#define KC 512            // k-rows per workgroup
#define BK 64             // k-rows per LDS tile
#define NTILES (KC / BK)  // 8
#define NSPLIT (KDIM / KC)// 16 k-splits
#define LSTR 130          // u32 stride per kp-row in LDS (128 + 2 pad)

typedef __fp16 half8 __attribute__((ext_vector_type(8)));
typedef float f32x4 __attribute__((ext_vector_type(4)));

__device__ __forceinline__ unsigned pk_u32(float a, float b) {
#if __has_builtin(__builtin_amdgcn_cvt_pkrtz)
  return __builtin_bit_cast(unsigned, __builtin_amdgcn_cvt_pkrtz(a, b));
#else
  __fp16 r2[2] = {(__fp16)a, (__fp16)b};
  return __builtin_bit_cast(unsigned, r2);
#endif
}

// ---------- pre-pass: pack x[32][8192] f32 -> A-fragment-major f16 (R4-validated) ----------
__global__ __launch_bounds__(256) void xpack_kernel(const float* __restrict__ x,
                                                    uint4* __restrict__ xpf) {
  const int T  = blockIdx.x * 256 + threadIdx.x;   // 0..32767
  const int sg = T >> 7;
  const int r  = T & 127;
  const int mt = r >> 6;
  const int L  = r & 63;
  const int m  = mt * 16 + (L & 15);
  const int k  = sg * 32 + (L >> 4) * 8;
  const float4* p = reinterpret_cast<const float4*>(x + (size_t)m * KDIM + k);
  float4 u0 = p[0], u1 = p[1];
  uint4 o;
  o.x = pk_u32(u0.x, u0.y);
  o.y = pk_u32(u0.z, u0.w);
  o.z = pk_u32(u1.x, u1.y);
  o.w = pk_u32(u1.z, u1.w);
  xpf[T] = o;
}

// ---------- fused Q4_0 fake-quant + MFMA GEMM ----------
// grid = (NDIM/NT, NSPLIT) = (64,16), block = 256 (4 waves).
__global__ __launch_bounds__(256, 4) void fused_q4_gemm(
    const uint4* __restrict__ xpf,     // packed x fragments
    const float* __restrict__ w,       // [8192][8192]
    const float* __restrict__ bias,    // [8192]
    float* __restrict__ out)           // [32][8192]
{
  __shared__ unsigned sW[32 * LSTR];   // 16.6 KB, [kp][n] half2 (k-pairs)

  const int t    = threadIdx.x;
  const int n0   = blockIdx.x * NT;
  const int k0   = blockIdx.y * KC;
  const int lane = t & 63;
  const int wv   = t >> 6;
  const int l15  = lane & 15;
  const int q    = lane >> 4;
  const int h    = lane >> 5;          // k-row parity within a load slab
  const int nl   = (lane & 31) * 4;    // first n (of 4) this lane owns in phase A

  f32x4 acc00 = {0.f, 0.f, 0.f, 0.f};
  f32x4 acc01 = {0.f, 0.f, 0.f, 0.f};
  f32x4 acc10 = {0.f, 0.f, 0.f, 0.f};
  f32x4 acc11 = {0.f, 0.f, 0.f, 0.f};

  float4 V[8];

  // prologue: fully-coalesced load of tile 0 (each instr = 1 KB contiguous)
#pragma unroll
  for (int p = 0; p < 8; ++p) {
    const int sp = p * 4 + wv;         // kp-row 0..31
    V[p] = *reinterpret_cast<const float4*>(
        w + (size_t)(k0 + 2 * sp + h) * NDIM + n0 + nl);
  }

  for (int tt = 0; tt < NTILES; ++tt) {
    const int kt = k0 + tt * BK;

    // ---- Phase A: butterfly block-scale, dequant, k-pair pack, LDS [kp][n] ----
#pragma unroll
    for (int p = 0; p < 8; ++p) {
      const int sp = p * 4 + wv;
      float4 v = V[p];
      // first-wins scan over own 4 consecutive n
      float ba = -1.0f, bv = 0.0f, a;
      a = fabsf(v.x); if (a > ba) { ba = a; bv = v.x; }
      a = fabsf(v.y); if (a > ba) { ba = a; bv = v.y; }
      a = fabsf(v.z); if (a > ba) { ba = a; bv = v.z; }
      a = fabsf(v.w); if (a > ba) { ba = a; bv = v.w; }
      // butterfly over the 8 lanes of this 32-n quant block (no exact ties in data)
#pragma unroll
      for (int msk = 1; msk <= 4; msk <<= 1) {
        float pa = __shfl_xor(ba, msk);
        float pv = __shfl_xor(bv, msk);
        if (pa > ba) { ba = pa; bv = pv; }
      }
      float d   = bv * -0.125f;
      float inv = (d == 0.0f) ? 0.0f : 1.0f / d;   // exact fp32 divide
      float s   = __half2float(__float2half(d));   // fp16 RTNE round-trip
      float q0f = fminf(fmaxf(truncf(fmaf(v.x, inv, 8.5f)), 0.0f), 15.0f);
      float q1f = fminf(fmaxf(truncf(fmaf(v.y, inv, 8.5f)), 0.0f), 15.0f);
      float q2f = fminf(fmaxf(truncf(fmaf(v.z, inv, 8.5f)), 0.0f), 15.0f);
      float q3f = fminf(fmaxf(truncf(fmaf(v.w, inv, 8.5f)), 0.0f), 15.0f);
      unsigned A = pk_u32((q0f - 8.0f) * s, (q1f - 8.0f) * s);  // (n0,n1) own k
      unsigned B = pk_u32((q2f - 8.0f) * s, (q3f - 8.0f) * s);  // (n2,n3) own k
      unsigned pA = (unsigned)__shfl_xor((int)A, 32);           // partner k
      unsigned pB = (unsigned)__shfl_xor((int)B, 32);
      unsigned lo0 = h ? pA : A, hi0 = h ? A : pA;
      unsigned lo1 = h ? pB : B, hi1 = h ? B : pB;
      unsigned D0 = (lo0 & 0xffffu) | (hi0 << 16);         // n0: (k_even, k_odd)
      unsigned D1 = (lo0 >> 16)     | (hi0 & 0xffff0000u); // n1
      unsigned D2 = (lo1 & 0xffffu) | (hi1 << 16);         // n2
      unsigned D3 = (lo1 >> 16)     | (hi1 & 0xffff0000u); // n3
      // lower half writes (n0,n1), upper half writes (n2,n3): b64, full coverage
      uint2 wr = h ? make_uint2(D2, D3) : make_uint2(D0, D1);
      *reinterpret_cast<uint2*>(&sW[sp * LSTR + nl + 2 * h]) = wr;
    }

    __syncthreads();   // A-writes visible before B-reads

    // ---- prefetch next tile's W into registers (overlaps phase B MFMA) ----
    if (tt + 1 < NTILES) {
#pragma unroll
      for (int p = 0; p < 8; ++p) {
        const int sp = p * 4 + wv;
        V[p] = *reinterpret_cast<const float4*>(
            w + (size_t)(kt + BK + 2 * sp + h) * NDIM + n0 + nl);
      }
    }

    // ---- Phase B: MFMA. A from packed global x, B from LDS (b32 x4, ≤2-way = free) ----
    const int sg0 = kt >> 5;
#pragma unroll
    for (int ks = 0; ks < 2; ++ks) {
      const uint4* ap = xpf + ((size_t)(sg0 + ks) * 2) * 64 + lane;
      uint4 a0u = ap[0];
      uint4 a1u = ap[64];
      const int kpb = ks * 16 + q * 4;
      const int nA = wv * 32 + l15;
      const int nB = nA + 16;
      uint4 b0u, b1u;
      b0u.x = sW[(kpb + 0) * LSTR + nA];
      b0u.y = sW[(kpb + 1) * LSTR + nA];
      b0u.z = sW[(kpb + 2) * LSTR + nA];
      b0u.w = sW[(kpb + 3) * LSTR + nA];
      b1u.x = sW[(kpb + 0) * LSTR + nB];
      b1u.y = sW[(kpb + 1) * LSTR + nB];
      b1u.z = sW[(kpb + 2) * LSTR + nB];
      b1u.w = sW[(kpb + 3) * LSTR + nB];
      half8 a0 = __builtin_bit_cast(half8, a0u);
      half8 a1 = __builtin_bit_cast(half8, a1u);
      half8 b0 = __builtin_bit_cast(half8, b0u);
      half8 b1 = __builtin_bit_cast(half8, b1u);
      acc00 = __builtin_amdgcn_mfma_f32_16x16x32_f16(a0, b0, acc00, 0, 0, 0);
      acc01 = __builtin_amdgcn_mfma_f32_16x16x32_f16(a0, b1, acc01, 0, 0, 0);
      acc10 = __builtin_amdgcn_mfma_f32_16x16x32_f16(a1, b0, acc10, 0, 0, 0);
      acc11 = __builtin_amdgcn_mfma_f32_16x16x32_f16(a1, b1, acc11, 0, 0, 0);
    }

    __syncthreads();   // B-reads done before next tile's A-writes
  }

  // ---- epilogue: k-split partials via atomics; split 0 folds bias (R4-proven) ----
  const int gn0 = n0 + wv * 32 + l15;
  const int gn1 = gn0 + 16;
  const float bv0 = (blockIdx.y == 0) ? bias[gn0] : 0.0f;
  const float bv1 = (blockIdx.y == 0) ? bias[gn1] : 0.0f;
#pragma unroll
  for (int r = 0; r < 4; ++r) {
    const int m0 = q * 4 + r;
    const int m1 = m0 + 16;
    atomicAdd(out + (size_t)m0 * NDIM + gn0, acc00[r] + bv0);
    atomicAdd(out + (size_t)m0 * NDIM + gn1, acc01[r] + bv1);
    atomicAdd(out + (size_t)m1 * NDIM + gn0, acc10[r] + bv0);
    atomicAdd(out + (size_t)m1 * NDIM + gn1, acc11[r] + bv1);
  }
}

extern "C" void kernel_launch(void* const* d_in, const int* in_sizes, int n_in,
                              void* d_out, int out_size, void* d_ws, size_t ws_size,
                              hipStream_t stream) {
  const float* x    = (const float*)d_in[0];   // [1,32,8192] f32
  const float* w    = (const float*)d_in[1];   // [8192,8192] f32
  const float* bias = (const float*)d_in[2];   // [8192] f32
  float* out  = (float*)d_out;                 // [1,32,8192] f32
  uint4* xpf  = (uint4*)d_ws;                  // 512 KB packed x fragments

  (void)hipMemsetAsync(out, 0, (size_t)MDIM * NDIM * sizeof(float), stream);
  xpack_kernel<<<128, 256, 0, stream>>>(x, xpf);

  dim3 grid(NDIM / NT, NSPLIT);
  fused_q4_gemm<<<grid, 256, 0, stream>>>(xpf, w, bias, out);
}